// Round 2
// baseline (330.862 us; speedup 1.0000x reference)
//
#include <hip/hip_runtime.h>

// Dtypes (established round 5): inputs int32/f32, outputs f32 (gid, score).
#define SS 4
#define BB 256
#define PP 32768
#define DD 256
#define QQ 1024          // SS*BB
#define NN 131072        // SS*PP candidate rows
#define KTOP 10
#define QTILE 128        // queries per block (4 waves x 32 q)
#define WQ 32            // q per wave (32x32 MFMA)
#define NCHUNK 64        // n-chunks
#define CHROWS 2048      // rows per chunk
#define PANEL 64         // rows per LDS panel
#define NPANEL (CHROWS / PANEL)   // 32
#define JCH 8            // per-(q,chunk) survivors (sorted desc run)
#define MSLOT 20         // global approx survivors per q (exact-rescored)
#define PANB (PANEL * DD * 2)     // 32768 B per panel buffer, LINEAR 512B rows
#define KEYMASK 0xFFFFF800u       // keep 21 score bits, low 11 = column
#define MWS 128          // merge-stage row stride in u32 (XOR-swizzled, fits 64KiB)
#define CVB 4096         // convert blocks (32 f32/thread)

typedef __attribute__((ext_vector_type(8))) short bf16x8;
typedef __attribute__((ext_vector_type(4))) short s16x4;
typedef __attribute__((ext_vector_type(4))) float f32x4;
typedef __attribute__((ext_vector_type(16))) float f32x16;
typedef __attribute__((ext_vector_type(4))) unsigned int u32x4;

static __device__ __forceinline__ short f2bf(float f) {   // RNE
    union { float f; unsigned u; } v; v.f = f;
    unsigned r = (v.u + 0x7FFFu + ((v.u >> 16) & 1u)) >> 16;
    return (short)r;
}
static __device__ __forceinline__ unsigned umax(unsigned a, unsigned b) { return a > b ? a : b; }
// v_med3_u32: for sorted a<=b, med3(k,a,b) == min(max(k,a),b). One VOP3 vs two.
static __device__ __forceinline__ unsigned med3u(unsigned k, unsigned a, unsigned b) {
    unsigned d;
    asm("v_med3_u32 %0, %1, %2, %3" : "=v"(d) : "v"(k), "v"(a), "v"(b));
    return d;
}

// ---------------- Stage 0: E f32->bf16 (lane-contiguous) AND qvec build ------------------
__global__ void prep_kernel(const int* __restrict__ rel, const int* __restrict__ head,
                            const float* __restrict__ E, const float* __restrict__ R,
                            short* __restrict__ Ebf, short* __restrict__ qbf) {
    if (blockIdx.x < CVB) {
        size_t base = (size_t)blockIdx.x * 8192;
        #pragma unroll
        for (int c = 0; c < 8; c++) {
            size_t idx = base + (size_t)c * 1024 + (size_t)threadIdx.x * 4;
            f32x4 a = *(const f32x4*)(E + idx);
            s16x4 o;
            o[0] = f2bf(a[0]); o[1] = f2bf(a[1]); o[2] = f2bf(a[2]); o[3] = f2bf(a[3]);
            *(s16x4*)(Ebf + idx) = o;
        }
    } else {
        int q = blockIdx.x - CVB, d = threadIdx.x;
        int s1 = q >> 8;
        float f = E[((size_t)(s1 * PP + head[q])) * DD + d] * R[(size_t)rel[q] * DD + d];
        qbf[q * DD + d] = f2bf(f);
    }
}

// ---------------- Stage 1: 32x32x16 bf16 MFMA + deferred packed-u32 top-k -----------------
// LDS: 2 linear panel buffers (64 rows x 512 B) = 65536 B, XOR-swizzled content:
//   logical 16B-granule (row, c) lives at LDS granule (row, c ^ (row&7)).
// Staged via global_load_lds (linear dest) with inverse-swizzled per-lane SOURCE.
// End-merge reuses the region: 4 waves x 32 q x 128-u32 (XOR bank swizzle) = 65536 B.
__launch_bounds__(256, 2)
__global__ void score_topk_kernel(const short* __restrict__ Ebf, const short* __restrict__ qbf,
                                  unsigned* __restrict__ parts) {
    __shared__ __align__(16) char smem[2 * PANB];

    const int tid  = threadIdx.x;
    const int wave = tid >> 6;
    const int lane = tid & 63;
    const int lh   = lane >> 5;   // k-half
    const int ln   = lane & 31;
    const int mtile = blockIdx.x >> 6;   // 0..7
    const int chunk = blockIdx.x & 63;   // 0..63
    // provably-uniform wave id for the LDS-DMA destination (must be SGPR)
    const int wavu = __builtin_amdgcn_readfirstlane(tid) >> 6;

    // A fragments: A[m=lane&31][k=ks*16 + (lane>>5)*8 + j]
    bf16x8 afrag[16];
    {
        const int arow = mtile * QTILE + wave * WQ + ln;
        #pragma unroll
        for (int ks = 0; ks < 16; ks++)
            afrag[ks] = *(const bf16x8*)(qbf + arow * DD + ks * 16 + lh * 8);
    }

    // 16 per-lane 4-deep ascending lists; list r holds q_local=(r&3)+8*(r>>2)+4*lh
    unsigned lst[16][4];
    #pragma unroll
    for (int r = 0; r < 16; r++)
        #pragma unroll
        for (int i = 0; i < 4; i++) lst[r][i] = 0u;

    // ds_read byte addresses (per lane, all panels via immediates):
    //   chain0 row=ln, chain1 row=ln+32 (+16384); buf1 (+32768). (ln+32)&7 == ln&7.
    int addrk[16];
    #pragma unroll
    for (int ks = 0; ks < 16; ks++)
        addrk[ks] = ln * 512 + ((((ks << 1) | lh) ^ (ln & 7)) << 4);

    // staging source offsets (bytes, inverse-swizzled): instr it writes LDS granules
    // g = (wavu*8+it)*64 + lane  ->  row=g>>5, cs=g&31; source col = cs ^ (row&7)
    int soff[8];
    #pragma unroll
    for (int it = 0; it < 8; it++) {
        int row = (((wavu * 8 + it) << 1) | lh);
        soff[it] = row * 512 + ((ln ^ (row & 7)) << 4);
    }

    const char* const pb = (const char*)(Ebf + (size_t)(chunk * CHROWS) * DD);

    #define STAGE(POFF, LOFF)                                                          \
        {                                                                              \
            _Pragma("unroll")                                                          \
            for (int it = 0; it < 8; it++)                                             \
                __builtin_amdgcn_global_load_lds(                                      \
                    (const __attribute__((address_space(1))) void*)(pb + (POFF) + soff[it]), \
                    (__attribute__((address_space(3))) void*)(smem + (LOFF) + (wavu * 8 + it) * 1024), \
                    16, 0, 0);                                                         \
        }

    #define MFMA_PANEL(A0, A1, LOFF)                                                   \
        {                                                                              \
            _Pragma("unroll")                                                          \
            for (int r = 0; r < 16; r++) { A0[r] = 256.0f; A1[r] = 256.0f; }           \
            _Pragma("unroll")                                                          \
            for (int ks = 0; ks < 16; ks++) {                                          \
                bf16x8 x0 = *(const bf16x8*)(smem + addrk[ks] + (LOFF));               \
                bf16x8 x1 = *(const bf16x8*)(smem + addrk[ks] + (LOFF) + 16384);       \
                A0 = __builtin_amdgcn_mfma_f32_32x32x16_bf16(afrag[ks], x0, A0, 0, 0, 0); \
                A1 = __builtin_amdgcn_mfma_f32_32x32x16_bf16(afrag[ks], x1, A1, 0, 0, 0); \
            }                                                                          \
        }

    #define KEYS(A0, A1, PIDX)                                                         \
        {                                                                              \
            const unsigned c0k = (unsigned)((PIDX) * 64 + ln);                         \
            const unsigned c1k = c0k + 32u;                                            \
            _Pragma("unroll")                                                          \
            for (int r = 0; r < 16; r++) {                                             \
                unsigned key = (__float_as_uint(A0[r]) & KEYMASK) | c0k;               \
                unsigned n0 = med3u(key, lst[r][0], lst[r][1]);                        \
                unsigned n1 = med3u(key, lst[r][1], lst[r][2]);                        \
                unsigned n2 = med3u(key, lst[r][2], lst[r][3]);                        \
                lst[r][3] = umax(key, lst[r][3]);                                      \
                lst[r][0] = n0; lst[r][1] = n1; lst[r][2] = n2;                        \
                key = (__float_as_uint(A1[r]) & KEYMASK) | c1k;                        \
                n0 = med3u(key, lst[r][0], lst[r][1]);                                 \
                n1 = med3u(key, lst[r][1], lst[r][2]);                                 \
                n2 = med3u(key, lst[r][2], lst[r][3]);                                 \
                lst[r][3] = umax(key, lst[r][3]);                                      \
                lst[r][0] = n0; lst[r][1] = n1; lst[r][2] = n2;                        \
            }                                                                          \
        }

    f32x16 accA0, accA1, accB0, accB1;

    STAGE(0, 0);                       // panel 0 -> buf0
    __syncthreads();                   // drains vmcnt: buf0 ready

    // 2 panels per iteration; keys of panel p-1 interleave with MFMAs of panel p
    for (int p = 0; p < NPANEL; p += 2) {
        STAGE((p + 1) * PANB, PANB);            // async loads into buf1
        MFMA_PANEL(accA0, accA1, 0);            // compute panel p from buf0
        if (p > 0) KEYS(accB0, accB1, p - 1);   // deferred keys (co-issue with MFMA)
        __syncthreads();                        // buf1 staged; buf0 reads done
        if (p + 2 < NPANEL) STAGE((p + 2) * PANB, 0);   // async loads into buf0
        MFMA_PANEL(accB0, accB1, PANB);         // compute panel p+1 from buf1
        KEYS(accA0, accA1, p);                  // deferred keys (co-issue with MFMA)
        __syncthreads();
    }
    KEYS(accB0, accB1, NPANEL - 1);             // epilogue: last panel's keys

    #undef STAGE
    #undef MFMA_PANEL
    #undef KEYS

    // ---- end of chunk: per-wave dump (32 q x 128 keys), lanes<32 build top-8 runs ----
    // region: wave*16384 B; row q stride 128 u32; bank spread via XOR (q&7)<<2
    unsigned* mw = (unsigned*)smem + (size_t)wave * (WQ * MWS);
    #pragma unroll
    for (int r = 0; r < 16; r++) {
        int q = (r & 3) + 8 * (r >> 2) + 4 * lh;
        u32x4 v; v[0] = lst[r][0]; v[1] = lst[r][1]; v[2] = lst[r][2]; v[3] = lst[r][3];
        *(u32x4*)(mw + q * MWS + ((ln * 4) ^ ((q & 7) << 2))) = v;  // same-wave LDS
    }
    if (lane < 32) {   // lane = q_local: top-8 of its 128 keys
        unsigned rr[JCH];
        #pragma unroll
        for (int i = 0; i < JCH; i++) rr[i] = 0u;
        #pragma unroll
        for (int j = 0; j < 32; j++) {
            u32x4 v = *(const u32x4*)(mw + lane * MWS + ((j * 4) ^ ((lane & 7) << 2)));
            #pragma unroll
            for (int e = 0; e < 4; e++) {
                unsigned x = v[e];
                unsigned t0 = med3u(x, rr[0], rr[1]);
                unsigned t1 = med3u(x, rr[1], rr[2]);
                unsigned t2 = med3u(x, rr[2], rr[3]);
                unsigned t3 = med3u(x, rr[3], rr[4]);
                unsigned t4 = med3u(x, rr[4], rr[5]);
                unsigned t5 = med3u(x, rr[5], rr[6]);
                unsigned t6 = med3u(x, rr[6], rr[7]);
                rr[7] = umax(x, rr[7]);
                rr[0]=t0; rr[1]=t1; rr[2]=t2; rr[3]=t3; rr[4]=t4; rr[5]=t5; rr[6]=t6;
            }
        }
        const int qg = mtile * QTILE + wave * WQ + lane;
        unsigned* dst = parts + ((size_t)qg * NCHUNK + chunk) * JCH;
        #pragma unroll
        for (int i = 0; i < JCH; i++) dst[i] = rr[JCH - 1 - i];   // descending run
    }
}

// ---------------- Stage 2: fused merge (lane=chunk, 20 pops) + exact f32 rescore ----------
__global__ void finalize_kernel(const int* __restrict__ rel, const int* __restrict__ head,
                                const float* __restrict__ E, const float* __restrict__ R,
                                const unsigned* __restrict__ parts, float* __restrict__ out) {
    __shared__ float qv[DD];
    __shared__ int   gl[MSLOT];
    __shared__ float rsc[MSLOT];
    __shared__ int   rgid[MSLOT];

    const int q = blockIdx.x;
    const int tid = threadIdx.x;
    const int wave = tid >> 6, lane = tid & 63;
    const int s1 = q >> 8;

    qv[tid] = E[((size_t)(s1 * PP + head[q])) * DD + tid] * R[(size_t)rel[q] * DD + tid];

    if (wave == 0) {   // lane = chunk; 20 argmax-pops over 64 sorted-desc runs of 8
        unsigned run[JCH];
        const unsigned* src = parts + ((size_t)q * NCHUNK + lane) * JCH;
        #pragma unroll
        for (int j = 0; j < JCH; j++) run[j] = src[j];
        for (int r = 0; r < MSLOT; r++) {
            unsigned best = run[0]; int bl = lane;
            #pragma unroll
            for (int off = 32; off >= 1; off >>= 1) {
                unsigned ob = __shfl_xor(best, off);
                int ol = __shfl_xor(bl, off);
                if (ob > best || (ob == best && ol < bl)) { best = ob; bl = ol; }
            }
            if (lane == bl) {
                int col = (int)(best & 0x7FFu);
                int n = lane * CHROWS + col;
                gl[r] = ((n & (PP - 1)) << 2) | (n >> 15);   // gid = p*4 + s2
                #pragma unroll
                for (int j = 0; j < JCH - 1; j++) run[j] = run[j + 1];
                run[JCH - 1] = 0u;
            }
        }
    }
    __syncthreads();

    // exact f32 rescore: wave w handles candidates w*5 .. w*5+4
    f32x4 qq = *(const f32x4*)(qv + lane * 4);
    #pragma unroll
    for (int c = 0; c < MSLOT / 4; c++) {
        int j = wave * (MSLOT / 4) + c;
        int gid = gl[j];
        int n = (gid & 3) * PP + (gid >> 2);
        f32x4 ev = *(const f32x4*)(E + (size_t)n * DD + lane * 4);
        f32x4 p = qq * ev;
        float s = (p[0] + p[1]) + (p[2] + p[3]);
        #pragma unroll
        for (int off = 32; off >= 1; off >>= 1) s += __shfl_xor(s, off);
        if (lane == 0) { rsc[j] = s; rgid[j] = gid; }
    }
    __syncthreads();

    if (tid < 64) {   // wave 0: 10 argmax-pops over 20 exact scores
        float a = (tid < MSLOT) ? rsc[tid] : -1e30f;
        int   g = (tid < MSLOT) ? rgid[tid] : 0;
        for (int r = 0; r < KTOP; r++) {
            float ps = a; int pg = g; int plm = tid;
            #pragma unroll
            for (int off = 32; off >= 1; off >>= 1) {
                float os = __shfl_xor(ps, off);
                int   og = __shfl_xor(pg, off);
                int   ol = __shfl_xor(plm, off);
                if (os > ps || (os == ps && ol < plm)) { ps = os; pg = og; plm = ol; }
            }
            if (tid == 0) {
                out[q * KTOP + r]             = (float)pg;   // Output 0: gid
                out[QQ * KTOP + q * KTOP + r] = ps;          // Output 1: score
            }
            if (tid == plm) a = -1e30f;
        }
    }
}

extern "C" void kernel_launch(void* const* d_in, const int* in_sizes, int n_in,
                              void* d_out, int out_size, void* d_ws, size_t ws_size,
                              hipStream_t stream) {
    const int*   rel  = (const int*)d_in[0];
    const int*   head = (const int*)d_in[1];
    const float* E    = (const float*)d_in[2];
    const float* R    = (const float*)d_in[3];

    char* ws = (char*)d_ws;
    short* Ebf = (short*)ws;                                   // 67,108,864 B
    short* qbf = (short*)(ws + (size_t)NN * DD * 2);           //    524,288 B
    unsigned* parts = (unsigned*)(ws + (size_t)NN * DD * 2 + (size_t)QQ * DD * 2);   // 2,097,152 B

    prep_kernel<<<dim3(CVB + QQ), dim3(256), 0, stream>>>(rel, head, E, R, Ebf, qbf);
    score_topk_kernel<<<dim3((QQ / QTILE) * NCHUNK), dim3(256), 0, stream>>>(Ebf, qbf, parts);
    finalize_kernel<<<dim3(QQ), dim3(256), 0, stream>>>(rel, head, E, R, parts, (float*)d_out);
}

// Round 3
// 297.108 us; speedup vs baseline: 1.1136x; 1.1136x over previous
//
#include <hip/hip_runtime.h>

// Dtypes (established round 5): inputs int32/f32, outputs f32 (gid, score).
#define SS 4
#define BB 256
#define PP 32768
#define DD 256
#define QQ 1024          // SS*BB
#define NN 131072        // SS*PP candidate rows
#define KTOP 10
#define QTILE 128        // queries per block (4 waves x 32 q)
#define WQ 32            // q per wave (32x32 MFMA)
#define NCHUNK 64        // n-chunks
#define CHROWS 2048      // rows per chunk
#define PANEL 64         // rows per LDS panel
#define NPANEL (CHROWS / PANEL)   // 32
#define JCH 8            // per-(q,chunk) survivors (sorted desc run)
#define MSLOT 20         // global approx survivors per q (exact-rescored)
#define ROWG 33          // padded LDS row stride in 16B granules (0-conflict, measured)
#define ROWE (ROWG * 8)  // row stride in bf16 units (264)
#define PANB (PANEL * ROWG * 16)  // 33792 B per panel buffer
#define KEYMASK 0xFFFFF800u       // keep 21 score bits, low 11 = column
#define MWS 132          // merge-stage row stride in u32 (bank-spread, 16B-aligned)
#define CVB 4096         // convert blocks (32 f32/thread)

typedef __attribute__((ext_vector_type(8))) short bf16x8;
typedef __attribute__((ext_vector_type(4))) short s16x4;
typedef __attribute__((ext_vector_type(4))) float f32x4;
typedef __attribute__((ext_vector_type(16))) float f32x16;
typedef __attribute__((ext_vector_type(4))) unsigned int u32x4;

static __device__ __forceinline__ short f2bf(float f) {   // RNE
    union { float f; unsigned u; } v; v.f = f;
    unsigned r = (v.u + 0x7FFFu + ((v.u >> 16) & 1u)) >> 16;
    return (short)r;
}
static __device__ __forceinline__ unsigned umax(unsigned a, unsigned b) { return a > b ? a : b; }
// v_med3_u32: for sorted a<=b, med3(k,a,b) == min(max(k,a),b). One VOP3 vs two.
static __device__ __forceinline__ unsigned med3u(unsigned k, unsigned a, unsigned b) {
    unsigned d;
    asm("v_med3_u32 %0, %1, %2, %3" : "=v"(d) : "v"(k), "v"(a), "v"(b));
    return d;
}

// ---------------- Stage 0: E f32->bf16 (lane-contiguous) AND qvec build ------------------
__global__ void prep_kernel(const int* __restrict__ rel, const int* __restrict__ head,
                            const float* __restrict__ E, const float* __restrict__ R,
                            short* __restrict__ Ebf, short* __restrict__ qbf) {
    if (blockIdx.x < CVB) {
        size_t base = (size_t)blockIdx.x * 8192;
        #pragma unroll
        for (int c = 0; c < 8; c++) {
            size_t idx = base + (size_t)c * 1024 + (size_t)threadIdx.x * 4;
            f32x4 a = *(const f32x4*)(E + idx);
            s16x4 o;
            o[0] = f2bf(a[0]); o[1] = f2bf(a[1]); o[2] = f2bf(a[2]); o[3] = f2bf(a[3]);
            *(s16x4*)(Ebf + idx) = o;
        }
    } else {
        int q = blockIdx.x - CVB, d = threadIdx.x;
        int s1 = q >> 8;
        float f = E[((size_t)(s1 * PP + head[q])) * DD + d] * R[(size_t)rel[q] * DD + d];
        qbf[q * DD + d] = f2bf(f);
    }
}

// ---------------- Stage 1: 32x32x16 bf16 MFMA (dual chains) + packed-u32 top-k ------------
__launch_bounds__(256, 2)
__global__ void score_topk_kernel(const short* __restrict__ Ebf, const short* __restrict__ qbf,
                                  unsigned* __restrict__ parts) {
    // LDS: 2 x panel buffers (64 rows x 33 granules x 16B) = 67584 B.
    // End-merge reuses the region: 4 waves x 32 q x 132-u32 stride = 67584 B.
    __shared__ __align__(16) char smem[2 * PANB];

    const int tid  = threadIdx.x;
    const int wave = tid >> 6;
    const int lane = tid & 63;
    const int lh   = lane >> 5;   // k-half
    const int ln   = lane & 31;
    const int mtile = blockIdx.x >> 6;   // 0..7
    const int chunk = blockIdx.x & 63;   // 0..63

    short* buf0 = (short*)smem;
    short* buf1 = (short*)(smem + PANB);

    // A fragments: A[m=lane&31][k=ks*16 + (lane>>5)*8 + j]
    bf16x8 afrag[16];
    {
        const int arow = mtile * QTILE + wave * WQ + ln;
        #pragma unroll
        for (int ks = 0; ks < 16; ks++)
            afrag[ks] = *(const bf16x8*)(qbf + arow * DD + ks * 16 + lh * 8);
    }

    // 16 per-lane 4-deep ascending lists; list r holds q_local=(r&3)+8*(r>>2)+4*lh
    unsigned lst[16][4];
    #pragma unroll
    for (int r = 0; r < 16; r++)
        #pragma unroll
        for (int i = 0; i < 4; i++) lst[r][i] = 0u;

    const int n0c = chunk * CHROWS;

    // prologue: stage panel 0 into buf0 (2048 granules / 256 threads = 8 each)
    bf16x8 st[8];
    #pragma unroll
    for (int it = 0; it < 8; it++) {
        int gi = it * 256 + tid, row = gi >> 5, slot = gi & 31;
        st[it] = *(const bf16x8*)(Ebf + (size_t)(n0c + row) * DD + slot * 8);
    }
    #pragma unroll
    for (int it = 0; it < 8; it++) {
        int gi = it * 256 + tid, row = gi >> 5, slot = gi & 31;
        *(bf16x8*)(buf0 + row * ROWE + slot * 8) = st[it];
    }

    for (int p = 0; p < NPANEL; p++) {
        short* bp = (p & 1) ? buf1 : buf0;
        short* bn = (p & 1) ? buf0 : buf1;
        __syncthreads();
        if (p + 1 < NPANEL) {   // prefetch next panel (overlaps compute)
            const int n1 = n0c + (p + 1) * PANEL;
            #pragma unroll
            for (int it = 0; it < 8; it++) {
                int gi = it * 256 + tid, row = gi >> 5, slot = gi & 31;
                st[it] = *(const bf16x8*)(Ebf + (size_t)(n1 + row) * DD + slot * 8);
            }
        }

        // two independent accumulator chains (cols ln and 32+ln), bias folded into C init
        f32x16 acc0, acc1;
        #pragma unroll
        for (int r = 0; r < 16; r++) { acc0[r] = 256.0f; acc1[r] = 256.0f; }
        const short* b0 = bp + ln * ROWE + lh * 8;
        const short* b1 = bp + (32 + ln) * ROWE + lh * 8;
        #pragma unroll
        for (int ks = 0; ks < 16; ks++) {
            bf16x8 x0 = *(const bf16x8*)(b0 + ks * 16);
            bf16x8 x1 = *(const bf16x8*)(b1 + ks * 16);
            acc0 = __builtin_amdgcn_mfma_f32_32x32x16_bf16(afrag[ks], x0, acc0, 0, 0, 0);
            acc1 = __builtin_amdgcn_mfma_f32_32x32x16_bf16(afrag[ks], x1, acc1, 0, 0, 0);
        }

        // D: col=lane&31, row=(reg&3)+8*(reg>>2)+4*lh -> one key per owned (q,col)
        const unsigned c0 = (unsigned)(p * 64 + ln);
        const unsigned c1 = (unsigned)(p * 64 + 32 + ln);
        #pragma unroll
        for (int r = 0; r < 16; r++) {
            unsigned key = (__float_as_uint(acc0[r]) & KEYMASK) | c0;
            unsigned n0 = med3u(key, lst[r][0], lst[r][1]);
            unsigned n1 = med3u(key, lst[r][1], lst[r][2]);
            unsigned n2 = med3u(key, lst[r][2], lst[r][3]);
            lst[r][3] = umax(key, lst[r][3]);
            lst[r][0] = n0; lst[r][1] = n1; lst[r][2] = n2;
        }
        #pragma unroll
        for (int r = 0; r < 16; r++) {
            unsigned key = (__float_as_uint(acc1[r]) & KEYMASK) | c1;
            unsigned n0 = med3u(key, lst[r][0], lst[r][1]);
            unsigned n1 = med3u(key, lst[r][1], lst[r][2]);
            unsigned n2 = med3u(key, lst[r][2], lst[r][3]);
            lst[r][3] = umax(key, lst[r][3]);
            lst[r][0] = n0; lst[r][1] = n1; lst[r][2] = n2;
        }

        if (p + 1 < NPANEL) {
            #pragma unroll
            for (int it = 0; it < 8; it++) {
                int gi = it * 256 + tid, row = gi >> 5, slot = gi & 31;
                *(bf16x8*)(bn + row * ROWE + slot * 8) = st[it];
            }
        }
    }

    // ---- end of chunk: per-wave dump (32 q x 128 keys), lanes<32 build top-8 runs ----
    __syncthreads();   // all panel reads complete; reuse whole smem
    unsigned* mw = (unsigned*)smem + (size_t)wave * (WQ * MWS);
    #pragma unroll
    for (int r = 0; r < 16; r++) {
        int q = (r & 3) + 8 * (r >> 2) + 4 * lh;
        u32x4 v; v[0] = lst[r][0]; v[1] = lst[r][1]; v[2] = lst[r][2]; v[3] = lst[r][3];
        *(u32x4*)(mw + q * MWS + ln * 4) = v;   // same-wave LDS, program-order visible
    }
    if (lane < 32) {   // lane = q_local: top-8 of its 128 keys
        unsigned rr[JCH];
        #pragma unroll
        for (int i = 0; i < JCH; i++) rr[i] = 0u;
        #pragma unroll
        for (int j = 0; j < 32; j++) {
            u32x4 v = *(const u32x4*)(mw + lane * MWS + j * 4);
            #pragma unroll
            for (int e = 0; e < 4; e++) {
                unsigned x = v[e];
                unsigned t0 = med3u(x, rr[0], rr[1]);
                unsigned t1 = med3u(x, rr[1], rr[2]);
                unsigned t2 = med3u(x, rr[2], rr[3]);
                unsigned t3 = med3u(x, rr[3], rr[4]);
                unsigned t4 = med3u(x, rr[4], rr[5]);
                unsigned t5 = med3u(x, rr[5], rr[6]);
                unsigned t6 = med3u(x, rr[6], rr[7]);
                rr[7] = umax(x, rr[7]);
                rr[0]=t0; rr[1]=t1; rr[2]=t2; rr[3]=t3; rr[4]=t4; rr[5]=t5; rr[6]=t6;
            }
        }
        const int qg = mtile * QTILE + wave * WQ + lane;
        unsigned* dst = parts + ((size_t)qg * NCHUNK + chunk) * JCH;
        #pragma unroll
        for (int i = 0; i < JCH; i++) dst[i] = rr[JCH - 1 - i];   // descending run
    }
}

// ---------------- Stage 2: fused merge (lane=chunk, 20 pops) + exact f32 rescore ----------
__global__ void finalize_kernel(const int* __restrict__ rel, const int* __restrict__ head,
                                const float* __restrict__ E, const float* __restrict__ R,
                                const unsigned* __restrict__ parts, float* __restrict__ out) {
    __shared__ float qv[DD];
    __shared__ int   gl[MSLOT];
    __shared__ float rsc[MSLOT];
    __shared__ int   rgid[MSLOT];

    const int q = blockIdx.x;
    const int tid = threadIdx.x;
    const int wave = tid >> 6, lane = tid & 63;
    const int s1 = q >> 8;

    qv[tid] = E[((size_t)(s1 * PP + head[q])) * DD + tid] * R[(size_t)rel[q] * DD + tid];

    if (wave == 0) {   // lane = chunk; 20 argmax-pops over 64 sorted-desc runs of 8
        unsigned run[JCH];
        const unsigned* src = parts + ((size_t)q * NCHUNK + lane) * JCH;
        #pragma unroll
        for (int j = 0; j < JCH; j++) run[j] = src[j];
        for (int r = 0; r < MSLOT; r++) {
            unsigned best = run[0]; int bl = lane;
            #pragma unroll
            for (int off = 32; off >= 1; off >>= 1) {
                unsigned ob = __shfl_xor(best, off);
                int ol = __shfl_xor(bl, off);
                if (ob > best || (ob == best && ol < bl)) { best = ob; bl = ol; }
            }
            if (lane == bl) {
                int col = (int)(best & 0x7FFu);
                int n = lane * CHROWS + col;
                gl[r] = ((n & (PP - 1)) << 2) | (n >> 15);   // gid = p*4 + s2
                #pragma unroll
                for (int j = 0; j < JCH - 1; j++) run[j] = run[j + 1];
                run[JCH - 1] = 0u;
            }
        }
    }
    __syncthreads();

    // exact f32 rescore: wave w handles candidates w*5 .. w*5+4
    f32x4 qq = *(const f32x4*)(qv + lane * 4);
    #pragma unroll
    for (int c = 0; c < MSLOT / 4; c++) {
        int j = wave * (MSLOT / 4) + c;
        int gid = gl[j];
        int n = (gid & 3) * PP + (gid >> 2);
        f32x4 ev = *(const f32x4*)(E + (size_t)n * DD + lane * 4);
        f32x4 p = qq * ev;
        float s = (p[0] + p[1]) + (p[2] + p[3]);
        #pragma unroll
        for (int off = 32; off >= 1; off >>= 1) s += __shfl_xor(s, off);
        if (lane == 0) { rsc[j] = s; rgid[j] = gid; }
    }
    __syncthreads();

    if (tid < 64) {   // wave 0: 10 argmax-pops over 20 exact scores
        float a = (tid < MSLOT) ? rsc[tid] : -1e30f;
        int   g = (tid < MSLOT) ? rgid[tid] : 0;
        for (int r = 0; r < KTOP; r++) {
            float ps = a; int pg = g; int plm = tid;
            #pragma unroll
            for (int off = 32; off >= 1; off >>= 1) {
                float os = __shfl_xor(ps, off);
                int   og = __shfl_xor(pg, off);
                int   ol = __shfl_xor(plm, off);
                if (os > ps || (os == ps && ol < plm)) { ps = os; pg = og; plm = ol; }
            }
            if (tid == 0) {
                out[q * KTOP + r]             = (float)pg;   // Output 0: gid
                out[QQ * KTOP + q * KTOP + r] = ps;          // Output 1: score
            }
            if (tid == plm) a = -1e30f;
        }
    }
}

extern "C" void kernel_launch(void* const* d_in, const int* in_sizes, int n_in,
                              void* d_out, int out_size, void* d_ws, size_t ws_size,
                              hipStream_t stream) {
    const int*   rel  = (const int*)d_in[0];
    const int*   head = (const int*)d_in[1];
    const float* E    = (const float*)d_in[2];
    const float* R    = (const float*)d_in[3];

    char* ws = (char*)d_ws;
    short* Ebf = (short*)ws;                                   // 67,108,864 B
    short* qbf = (short*)(ws + (size_t)NN * DD * 2);           //    524,288 B
    unsigned* parts = (unsigned*)(ws + (size_t)NN * DD * 2 + (size_t)QQ * DD * 2);   // 2,097,152 B

    prep_kernel<<<dim3(CVB + QQ), dim3(256), 0, stream>>>(rel, head, E, R, Ebf, qbf);
    score_topk_kernel<<<dim3((QQ / QTILE) * NCHUNK), dim3(256), 0, stream>>>(Ebf, qbf, parts);
    finalize_kernel<<<dim3(QQ), dim3(256), 0, stream>>>(rel, head, E, R, parts, (float*)d_out);
}